// Round 3
// baseline (16917.657 us; speedup 1.0000x reference)
//
#include <hip/hip_runtime.h>

#define PAD_IDX 0

typedef __attribute__((ext_vector_type(8))) short short8;
typedef __attribute__((ext_vector_type(4))) float f32x4;

// ---------- helpers ----------
__device__ __forceinline__ unsigned short f32_to_bf16_rne(float f) {
  unsigned int u = __builtin_bit_cast(unsigned int, f);
  u += 0x7FFFu + ((u >> 16) & 1u);
  return (unsigned short)(u >> 16);
}

__device__ __forceinline__ void load16_to_lds(const void* g, void* lds) {
  __builtin_amdgcn_global_load_lds(
      (const __attribute__((address_space(1))) unsigned int*)g,
      (__attribute__((address_space(3))) unsigned int*)lds,
      16, 0, 0);
}

// ---------- kernel 0: sentinel (only if ws too small) ----------
__global__ void sentinel_kernel(float* out) { out[0] = 1.0e6f; }

// ---------- kernel 1: lm_W f32 -> bf16 ----------
__global__ __launch_bounds__(256) void cvt_kernel(const float* __restrict__ in,
                                                  unsigned short* __restrict__ out,
                                                  int n8) {
  int stride = gridDim.x * blockDim.x;
  for (int i = blockIdx.x * blockDim.x + threadIdx.x; i < n8; i += stride) {
    float4 a = ((const float4*)in)[2 * i];
    float4 b = ((const float4*)in)[2 * i + 1];
    ushort4 lo, hi;
    lo.x = f32_to_bf16_rne(a.x); lo.y = f32_to_bf16_rne(a.y);
    lo.z = f32_to_bf16_rne(a.z); lo.w = f32_to_bf16_rne(a.w);
    hi.x = f32_to_bf16_rne(b.x); hi.y = f32_to_bf16_rne(b.y);
    hi.z = f32_to_bf16_rne(b.z); hi.w = f32_to_bf16_rne(b.w);
    ((ushort4*)out)[2 * i] = lo;
    ((ushort4*)out)[2 * i + 1] = hi;
  }
}

// ---------- kernel 2: xw[r][j] = emb[tok[r]] . Wx[j] + bias[j]  (f32) ----------
__global__ __launch_bounds__(256) void xw_kernel(const int* __restrict__ tok,
                                                 const float* __restrict__ emb,
                                                 const float* __restrict__ Wx,
                                                 const float* __restrict__ bias,
                                                 float* __restrict__ xw) {
  __shared__ float At[32][68];  // [k][m], padded
  __shared__ float Bt[32][68];  // [k][n]
  __shared__ int stok[64];
  int tid = threadIdx.x;
  int tm = blockIdx.x & 63;
  int tn = blockIdx.x >> 6;
  int r0 = tm * 64, j0 = tn * 64;
  if (tid < 64) stok[tid] = tok[r0 + tid];
  int tx = tid & 15, ty = tid >> 4;
  float acc[4][4] = {};
  for (int kt = 0; kt < 512; kt += 32) {
    __syncthreads();
    #pragma unroll
    for (int ii = 0; ii < 2; ++ii) {
      int idx = tid * 2 + ii;
      int m = idx >> 3, fv = idx & 7;
      float4 va = *(const float4*)&emb[(size_t)stok[m] * 512 + kt + fv * 4];
      float4 vb = *(const float4*)&Wx[(size_t)(j0 + m) * 512 + kt + fv * 4];
      At[fv * 4 + 0][m] = va.x; At[fv * 4 + 1][m] = va.y;
      At[fv * 4 + 2][m] = va.z; At[fv * 4 + 3][m] = va.w;
      Bt[fv * 4 + 0][m] = vb.x; Bt[fv * 4 + 1][m] = vb.y;
      Bt[fv * 4 + 2][m] = vb.z; Bt[fv * 4 + 3][m] = vb.w;
    }
    __syncthreads();
    #pragma unroll
    for (int k = 0; k < 32; ++k) {
      float4 a4 = *(const float4*)&At[k][ty * 4];
      float4 b4 = *(const float4*)&Bt[k][tx * 4];
      float av[4] = {a4.x, a4.y, a4.z, a4.w};
      float bv[4] = {b4.x, b4.y, b4.z, b4.w};
      #pragma unroll
      for (int i = 0; i < 4; ++i)
        #pragma unroll
        for (int jj = 0; jj < 4; ++jj) acc[i][jj] = fmaf(av[i], bv[jj], acc[i][jj]);
    }
  }
  #pragma unroll
  for (int i = 0; i < 4; ++i) {
    size_t row = (size_t)(r0 + ty * 4 + i) * 1024 + j0 + tx * 4;
    #pragma unroll
    for (int jj = 0; jj < 4; ++jj)
      xw[row + jj] = acc[i][jj] + bias[j0 + tx * 4 + jj];
  }
}

// ---------- kernel 3: recurrence ----------
// 256 WGs x 512 threads, 1 WG/CU. chain c = blk&15 (all 16 WGs of a chain land on
// XCD c%8 under round-robin dispatch), wg g = blk>>4 owns rows g*64..+63.
// Thread (jj=tid>>5, kk=tid&31): rows jj*4..+3, k-slice kk*32..+31.
// Weights = 32 NAMED f32x4 vars (no alloca -> no scratch spill; VGPR tell ~190).
// Sync: per-WG flag slot (64B stride), release-store t+1; 16-lane relaxed poll.
__global__ __launch_bounds__(512, 2) void rec_kernel(const float* __restrict__ Wh,
                                                     const float* __restrict__ xw,
                                                     const int* __restrict__ tok,
                                                     float* hbuf,            // [2][16][1024]
                                                     unsigned short* __restrict__ h_all,
                                                     unsigned int* flags) {  // [16][16] stride 16u32
  int c = blockIdx.x & 15;
  int g = blockIdx.x >> 4;
  int tid = threadIdx.x;
  int kk = tid & 31, jj = tid >> 5;
  int jb = g * 64 + jj * 4;

  const float* wb = Wh + (size_t)jb * 1024 + kk * 32;
#define LDW(r, i) f32x4 w##r##i = *(const f32x4*)(wb + r * 1024 + i * 4);
#define LDROW(r) LDW(r,0) LDW(r,1) LDW(r,2) LDW(r,3) LDW(r,4) LDW(r,5) LDW(r,6) LDW(r,7)
  LDROW(0) LDROW(1) LDROW(2) LDROW(3)
#undef LDROW
#undef LDW

  __shared__ float hs[1152];  // 32 slices x 36 floats (padded)
  float* h0 = hbuf + c * 1024;
  float* h1 = hbuf + 16 * 1024 + c * 1024;

  for (int t = 0; t < 256; ++t) {
    // prefetch (independent of barrier; hides under the spin)
    size_t rowoff = ((size_t)c * 256 + t) * 1024 + jb;
    float4 xv = {0.f, 0.f, 0.f, 0.f};
    int tkn = 1;
    if (kk == 0) {
      xv = *(const float4*)(xw + rowoff);
      tkn = tok[c * 256 + t];
    }
    if (t > 0 && tid < 16) {
      const unsigned int target = (unsigned int)t;
      unsigned int* fp = flags + (c * 16 + tid) * 16;
      int guard = 0;
      while (__hip_atomic_load(fp, __ATOMIC_RELAXED, __HIP_MEMORY_SCOPE_AGENT) < target) {
        __builtin_amdgcn_s_sleep(1);
        if (++guard > (1 << 20)) break;  // fail loud, not hung
      }
    }
    __threadfence();   // acquire: no staging load drifts above the poll
    __syncthreads();

    const float* hin = (t & 1) ? h1 : h0;
    float* hout = (t & 1) ? h0 : h1;
    if (tid < 256) {
      const float* src = hin + tid * 4;
      float4 v;
      v.x = __hip_atomic_load(src + 0, __ATOMIC_RELAXED, __HIP_MEMORY_SCOPE_AGENT);
      v.y = __hip_atomic_load(src + 1, __ATOMIC_RELAXED, __HIP_MEMORY_SCOPE_AGENT);
      v.z = __hip_atomic_load(src + 2, __ATOMIC_RELAXED, __HIP_MEMORY_SCOPE_AGENT);
      v.w = __hip_atomic_load(src + 3, __ATOMIC_RELAXED, __HIP_MEMORY_SCOPE_AGENT);
      *(float4*)&hs[(tid >> 3) * 36 + (tid & 7) * 4] = v;
    }
    __syncthreads();

    const float* hp = hs + kk * 36;
    f32x4 a0 = {0.f, 0.f, 0.f, 0.f}, a1 = a0, a2 = a0, a3 = a0;
#define FMAI(i) { f32x4 h4 = *(const f32x4*)(hp + i * 4); \
    a0 += w0##i * h4; a1 += w1##i * h4; a2 += w2##i * h4; a3 += w3##i * h4; }
    FMAI(0) FMAI(1) FMAI(2) FMAI(3) FMAI(4) FMAI(5) FMAI(6) FMAI(7)
#undef FMAI
    float s0 = (a0[0] + a0[1]) + (a0[2] + a0[3]);
    float s1 = (a1[0] + a1[1]) + (a1[2] + a1[3]);
    float s2 = (a2[0] + a2[1]) + (a2[2] + a2[3]);
    float s3 = (a3[0] + a3[1]) + (a3[2] + a3[3]);
    #pragma unroll
    for (int m = 1; m <= 16; m <<= 1) {
      s0 += __shfl_xor(s0, m);
      s1 += __shfl_xor(s1, m);
      s2 += __shfl_xor(s2, m);
      s3 += __shfl_xor(s3, m);
    }

    if (kk == 0) {
      float o0 = hs[((jb + 0) >> 5) * 36 + ((jb + 0) & 31)];
      float o1 = hs[((jb + 1) >> 5) * 36 + ((jb + 1) & 31)];
      float o2 = hs[((jb + 2) >> 5) * 36 + ((jb + 2) & 31)];
      float o3 = hs[((jb + 3) >> 5) * 36 + ((jb + 3) & 31)];
      float n0, n1, n2, n3;
      if (tkn != PAD_IDX) {
        n0 = tanhf(xv.x + s0); n1 = tanhf(xv.y + s1);
        n2 = tanhf(xv.z + s2); n3 = tanhf(xv.w + s3);
      } else {
        n0 = o0; n1 = o1; n2 = o2; n3 = o3;
      }
      __hip_atomic_store(hout + jb + 0, n0, __ATOMIC_RELAXED, __HIP_MEMORY_SCOPE_AGENT);
      __hip_atomic_store(hout + jb + 1, n1, __ATOMIC_RELAXED, __HIP_MEMORY_SCOPE_AGENT);
      __hip_atomic_store(hout + jb + 2, n2, __ATOMIC_RELAXED, __HIP_MEMORY_SCOPE_AGENT);
      __hip_atomic_store(hout + jb + 3, n3, __ATOMIC_RELAXED, __HIP_MEMORY_SCOPE_AGENT);
      ushort4 hb;
      hb.x = f32_to_bf16_rne(n0); hb.y = f32_to_bf16_rne(n1);
      hb.z = f32_to_bf16_rne(n2); hb.w = f32_to_bf16_rne(n3);
      *(ushort4*)&h_all[rowoff] = hb;
    }
    __threadfence();   // order h stores before the flag release (coop-groups pattern)
    __syncthreads();
    if (tid == 0)
      __hip_atomic_store(flags + (c * 16 + g) * 16, (unsigned int)(t + 1),
                         __ATOMIC_RELEASE, __HIP_MEMORY_SCOPE_AGENT);
  }
}

// ---------- kernel 4: logits = h_all(bf16) @ lm_W(bf16)^T, f32 out ----------
__global__ __launch_bounds__(256) void gemm_kernel(const unsigned short* __restrict__ A,
                                                   const unsigned short* __restrict__ B,
                                                   float* __restrict__ C) {
  __shared__ unsigned short sA[128 * 64];
  __shared__ unsigned short sB[128 * 64];
  int tid = threadIdx.x;
  int lane = tid & 63, wave = tid >> 6;
  int id = blockIdx.x;
  int s = (id & 7) * 1000 + (id >> 3);  // bijective XCD swizzle (8000 % 8 == 0)
  int tm = s & 31, tn = s >> 5;
  int r0 = tm * 128, c0 = tn * 128;
  int wm = wave >> 1, wn = wave & 1;
  f32x4 zero = {0.f, 0.f, 0.f, 0.f};
  f32x4 acc[4][4];
  #pragma unroll
  for (int i = 0; i < 4; ++i)
    #pragma unroll
    for (int jx = 0; jx < 4; ++jx) acc[i][jx] = zero;

  for (int kt = 0; kt < 16; ++kt) {
    __syncthreads();
    #pragma unroll
    for (int i = 0; i < 4; ++i) {
      int slot = i * 256 + tid;
      int m = slot >> 3, sg = slot & 7;
      int kg = sg ^ (m & 7);
      const unsigned short* ga = A + (size_t)(r0 + m) * 1024 + kt * 64 + kg * 8;
      load16_to_lds(ga, &sA[(i * 256 + wave * 64) * 8]);
      const unsigned short* gb = B + (size_t)(c0 + m) * 1024 + kt * 64 + kg * 8;
      load16_to_lds(gb, &sB[(i * 256 + wave * 64) * 8]);
    }
    __syncthreads();
    #pragma unroll
    for (int kkb = 0; kkb < 2; ++kkb) {
      short8 af[4], bf[4];
      int kbyte = kkb * 64 + (lane >> 4) * 16;
      #pragma unroll
      for (int i = 0; i < 4; ++i) {
        int row = wm * 64 + i * 16 + (lane & 15);
        int off = row * 128 + (kbyte ^ ((row & 7) << 4));
        af[i] = *(const short8*)((const char*)sA + off);
        int rowb = wn * 64 + i * 16 + (lane & 15);
        int offb = rowb * 128 + (kbyte ^ ((rowb & 7) << 4));
        bf[i] = *(const short8*)((const char*)sB + offb);
      }
      #pragma unroll
      for (int i = 0; i < 4; ++i)
        #pragma unroll
        for (int jx = 0; jx < 4; ++jx)
          acc[i][jx] = __builtin_amdgcn_mfma_f32_16x16x32_bf16(af[i], bf[jx], acc[i][jx], 0, 0, 0);
    }
  }
  int rbase = r0 + wm * 64 + (lane >> 4) * 4;
  int cbase = c0 + wn * 64 + (lane & 15);
  #pragma unroll
  for (int i = 0; i < 4; ++i)
    #pragma unroll
    for (int jx = 0; jx < 4; ++jx)
      #pragma unroll
      for (int q = 0; q < 4; ++q)
        C[(size_t)(rbase + i * 16 + q) * 32000 + cbase + jx * 16] = acc[i][jx][q];
}

// ---------- launch ----------
extern "C" void kernel_launch(void* const* d_in, const int* in_sizes, int n_in,
                              void* d_out, int out_size, void* d_ws, size_t ws_size,
                              hipStream_t stream) {
  const int* tok = (const int*)d_in[0];
  const float* emb = (const float*)d_in[1];
  const float* Wx = (const float*)d_in[2];
  const float* Wh = (const float*)d_in[3];
  const float* bias = (const float*)d_in[4];
  const float* lmW = (const float*)d_in[5];
  float* out = (float*)d_out;

  const size_t OFF_LMW = 0;                       // bf16 lm_W: 65,536,000
  const size_t OFF_XW = 65536000;                 // f32 xw:   16,777,216
  const size_t OFF_HALL = OFF_XW + 16777216;      // bf16 h_all: 8,388,608
  const size_t OFF_HBUF = OFF_HALL + 8388608;     // f32 hbuf: 131,072
  const size_t OFF_FLG = OFF_HBUF + 131072;       // u32 flags: 16*16*16*4 = 16,384
  const size_t NEED = OFF_FLG + 16384;
  if (ws_size < NEED) {
    sentinel_kernel<<<1, 1, 0, stream>>>(out);
    return;
  }
  char* ws = (char*)d_ws;
  unsigned short* lmW_bf = (unsigned short*)(ws + OFF_LMW);
  float* xw = (float*)(ws + OFF_XW);
  unsigned short* h_all = (unsigned short*)(ws + OFF_HALL);
  float* hbuf = (float*)(ws + OFF_HBUF);
  unsigned int* flags = (unsigned int*)(ws + OFF_FLG);

  hipMemsetAsync(ws + OFF_HBUF, 0, 131072 + 16384, stream);  // h0 = 0, flags = 0 (every call!)
  cvt_kernel<<<2048, 256, 0, stream>>>(lmW, lmW_bf, 32000 * 1024 / 8);
  xw_kernel<<<1024, 256, 0, stream>>>(tok, emb, Wx, bias, xw);
  rec_kernel<<<256, 512, 0, stream>>>(Wh, xw, tok, hbuf, h_all, flags);
  gemm_kernel<<<8000, 256, 0, stream>>>(h_all, lmW_bf, out);
}

// Round 4
// 1058.109 us; speedup vs baseline: 15.9886x; 15.9886x over previous
//
#include <hip/hip_runtime.h>

#define PAD_IDX 0

typedef __attribute__((ext_vector_type(8))) short short8;
typedef __attribute__((ext_vector_type(4))) float f32x4;

// ---------- helpers ----------
__device__ __forceinline__ unsigned short f32_to_bf16_rne(float f) {
  unsigned int u = __builtin_bit_cast(unsigned int, f);
  u += 0x7FFFu + ((u >> 16) & 1u);
  return (unsigned short)(u >> 16);
}

__device__ __forceinline__ void load16_to_lds(const void* g, void* lds) {
  __builtin_amdgcn_global_load_lds(
      (const __attribute__((address_space(1))) unsigned int*)g,
      (__attribute__((address_space(3))) unsigned int*)lds,
      16, 0, 0);
}

// ---------- kernel 0: sentinel (only if ws too small) ----------
__global__ void sentinel_kernel(float* out) { out[0] = 1.0e6f; }

// ---------- kernel 1: lm_W f32 -> bf16 ----------
__global__ __launch_bounds__(256) void cvt_kernel(const float* __restrict__ in,
                                                  unsigned short* __restrict__ out,
                                                  int n8) {
  int stride = gridDim.x * blockDim.x;
  for (int i = blockIdx.x * blockDim.x + threadIdx.x; i < n8; i += stride) {
    float4 a = ((const float4*)in)[2 * i];
    float4 b = ((const float4*)in)[2 * i + 1];
    ushort4 lo, hi;
    lo.x = f32_to_bf16_rne(a.x); lo.y = f32_to_bf16_rne(a.y);
    lo.z = f32_to_bf16_rne(a.z); lo.w = f32_to_bf16_rne(a.w);
    hi.x = f32_to_bf16_rne(b.x); hi.y = f32_to_bf16_rne(b.y);
    hi.z = f32_to_bf16_rne(b.z); hi.w = f32_to_bf16_rne(b.w);
    ((ushort4*)out)[2 * i] = lo;
    ((ushort4*)out)[2 * i + 1] = hi;
  }
}

// ---------- kernel 2: xw[r][j] = emb[tok[r]] . Wx[j] + bias[j]  (f32) ----------
__global__ __launch_bounds__(256) void xw_kernel(const int* __restrict__ tok,
                                                 const float* __restrict__ emb,
                                                 const float* __restrict__ Wx,
                                                 const float* __restrict__ bias,
                                                 float* __restrict__ xw) {
  __shared__ float At[32][68];  // [k][m], padded
  __shared__ float Bt[32][68];  // [k][n]
  __shared__ int stok[64];
  int tid = threadIdx.x;
  int tm = blockIdx.x & 63;
  int tn = blockIdx.x >> 6;
  int r0 = tm * 64, j0 = tn * 64;
  if (tid < 64) stok[tid] = tok[r0 + tid];
  int tx = tid & 15, ty = tid >> 4;
  float acc[4][4] = {};
  for (int kt = 0; kt < 512; kt += 32) {
    __syncthreads();
    #pragma unroll
    for (int ii = 0; ii < 2; ++ii) {
      int idx = tid * 2 + ii;
      int m = idx >> 3, fv = idx & 7;
      float4 va = *(const float4*)&emb[(size_t)stok[m] * 512 + kt + fv * 4];
      float4 vb = *(const float4*)&Wx[(size_t)(j0 + m) * 512 + kt + fv * 4];
      At[fv * 4 + 0][m] = va.x; At[fv * 4 + 1][m] = va.y;
      At[fv * 4 + 2][m] = va.z; At[fv * 4 + 3][m] = va.w;
      Bt[fv * 4 + 0][m] = vb.x; Bt[fv * 4 + 1][m] = vb.y;
      Bt[fv * 4 + 2][m] = vb.z; Bt[fv * 4 + 3][m] = vb.w;
    }
    __syncthreads();
    #pragma unroll
    for (int k = 0; k < 32; ++k) {
      float4 a4 = *(const float4*)&At[k][ty * 4];
      float4 b4 = *(const float4*)&Bt[k][tx * 4];
      float av[4] = {a4.x, a4.y, a4.z, a4.w};
      float bv[4] = {b4.x, b4.y, b4.z, b4.w};
      #pragma unroll
      for (int i = 0; i < 4; ++i)
        #pragma unroll
        for (int jj = 0; jj < 4; ++jj) acc[i][jj] = fmaf(av[i], bv[jj], acc[i][jj]);
    }
  }
  #pragma unroll
  for (int i = 0; i < 4; ++i) {
    size_t row = (size_t)(r0 + ty * 4 + i) * 1024 + j0 + tx * 4;
    #pragma unroll
    for (int jj = 0; jj < 4; ++jj)
      xw[row + jj] = acc[i][jj] + bias[j0 + tx * 4 + jj];
  }
}

// ---------- kernel 3: recurrence ----------
// 256 WGs x 1024 threads, 1 WG/CU (16 waves, VGPR cap 128 -> design needs ~100).
// chain c = blk&15, wg g = blk>>4 owns rows g*64..+63.
// Thread (row = tid>>4, kk = tid&15): output row g*64+row, k-slice kk*64..+63
// -> 16 named f32x4 weights (64 VGPRs). Shuffle-reduce over 16 kk-lanes.
// Sync: FUSED data+tag u64 {tag, h_bits}. Producer: one relaxed agent store.
// Consumer: thread tid polls its own slot until tag==t (data in same load).
// Parity double-buffer (hcomb[2][16][1024]) makes tag reuse race-free.
// tanh via v_exp_f32 (inline, no lib call): 1 - 2/(exp2(2x*log2e)+1).
__global__ __launch_bounds__(1024, 4) void rec_kernel(const float* __restrict__ Wh,
                                                      const float* __restrict__ xw,
                                                      const int* __restrict__ tok,
                                                      unsigned long long* hcomb,  // [2][16][1024]
                                                      unsigned short* __restrict__ h_all) {
  int c = blockIdx.x & 15;
  int g = blockIdx.x >> 4;
  int tid = threadIdx.x;
  int kk = tid & 15;
  int j = g * 64 + (tid >> 4);   // this thread-group's output row

  const float* wb = Wh + (size_t)j * 1024 + kk * 64;
#define LDW(i) f32x4 w##i = *(const f32x4*)(wb + i * 4);
  LDW(0) LDW(1) LDW(2) LDW(3) LDW(4) LDW(5) LDW(6) LDW(7)
  LDW(8) LDW(9) LDW(10) LDW(11) LDW(12) LDW(13) LDW(14) LDW(15)
#undef LDW

  __shared__ float hs[16 * 68];  // 16 slices x 64 (+4 pad)
  int lidx = (tid >> 6) * 68 + (tid & 63);  // staging slot: h[tid] -> hs[lidx]
  unsigned long long* hc0 = hcomb + (size_t)c * 1024;
  unsigned long long* hc1 = hcomb + 16 * 1024 + (size_t)c * 1024;
  bool writer = (kk == 0);

  for (int t = 0; t < 256; ++t) {
    // prefetch (hides under the poll)
    float xv = 0.f;
    int tkn = 1;
    if (writer) {
      xv = xw[((size_t)c * 256 + t) * 1024 + j];
      tkn = tok[c * 256 + t];
    }
    // poll own slot: tag==t means step-t data present in the same 8B load
    unsigned long long* src = ((t & 1) ? hc1 : hc0) + tid;
    unsigned long long v;
    int guard = 0;
    do {
      v = __hip_atomic_load(src, __ATOMIC_RELAXED, __HIP_MEMORY_SCOPE_AGENT);
      if ((unsigned int)(v >> 32) == (unsigned int)t) break;
      __builtin_amdgcn_s_sleep(1);
    } while (++guard < (1 << 20));  // fail loud (absmax), not hung
    hs[lidx] = __builtin_bit_cast(float, (unsigned int)v);
    __asm__ volatile("s_waitcnt lgkmcnt(0)\n\ts_barrier" ::: "memory");  // no vmcnt drain

    const float* hp = hs + kk * 68;
    f32x4 a0 = {0.f, 0.f, 0.f, 0.f}, a1 = a0, a2 = a0, a3 = a0;
#define FMAI(i, acc) { f32x4 h4 = *(const f32x4*)(hp + i * 4); acc += w##i * h4; }
    FMAI(0, a0) FMAI(1, a1) FMAI(2, a2) FMAI(3, a3)
    FMAI(4, a0) FMAI(5, a1) FMAI(6, a2) FMAI(7, a3)
    FMAI(8, a0) FMAI(9, a1) FMAI(10, a2) FMAI(11, a3)
    FMAI(12, a0) FMAI(13, a1) FMAI(14, a2) FMAI(15, a3)
#undef FMAI
    f32x4 aa = (a0 + a1) + (a2 + a3);
    float s = (aa[0] + aa[1]) + (aa[2] + aa[3]);
    s += __shfl_xor(s, 1);
    s += __shfl_xor(s, 2);
    s += __shfl_xor(s, 4);
    s += __shfl_xor(s, 8);

    if (writer) {
      float hnew;
      if (tkn != PAD_IDX) {
        float pre = xv + s;
        float e = __builtin_amdgcn_exp2f(pre * 2.8853900817779268f);  // exp(2x)
        hnew = 1.0f - 2.0f / (e + 1.0f);                              // tanh(x)
      } else {
        hnew = hs[(j >> 6) * 68 + (j & 63)];  // keep old h at pad
      }
      unsigned long long pv =
          ((unsigned long long)(unsigned int)(t + 1) << 32) |
          (unsigned long long)__builtin_bit_cast(unsigned int, hnew);
      __hip_atomic_store((((t + 1) & 1) ? hc1 : hc0) + j, pv,
                         __ATOMIC_RELAXED, __HIP_MEMORY_SCOPE_AGENT);
      h_all[((size_t)c * 256 + t) * 1024 + j] = f32_to_bf16_rne(hnew);
    }
    __asm__ volatile("s_waitcnt lgkmcnt(0)\n\ts_barrier" ::: "memory");  // hs reuse guard
  }
}

// ---------- kernel 4: logits = h_all(bf16) @ lm_W(bf16)^T, f32 out ----------
__global__ __launch_bounds__(256) void gemm_kernel(const unsigned short* __restrict__ A,
                                                   const unsigned short* __restrict__ B,
                                                   float* __restrict__ C) {
  __shared__ unsigned short sA[128 * 64];
  __shared__ unsigned short sB[128 * 64];
  int tid = threadIdx.x;
  int lane = tid & 63, wave = tid >> 6;
  int id = blockIdx.x;
  int s = (id & 7) * 1000 + (id >> 3);  // bijective XCD swizzle (8000 % 8 == 0)
  int tm = s & 31, tn = s >> 5;
  int r0 = tm * 128, c0 = tn * 128;
  int wm = wave >> 1, wn = wave & 1;
  f32x4 zero = {0.f, 0.f, 0.f, 0.f};
  f32x4 acc[4][4];
  #pragma unroll
  for (int i = 0; i < 4; ++i)
    #pragma unroll
    for (int jx = 0; jx < 4; ++jx) acc[i][jx] = zero;

  for (int kt = 0; kt < 16; ++kt) {
    __syncthreads();
    #pragma unroll
    for (int i = 0; i < 4; ++i) {
      int slot = i * 256 + tid;
      int m = slot >> 3, sg = slot & 7;
      int kg = sg ^ (m & 7);
      const unsigned short* ga = A + (size_t)(r0 + m) * 1024 + kt * 64 + kg * 8;
      load16_to_lds(ga, &sA[(i * 256 + wave * 64) * 8]);
      const unsigned short* gb = B + (size_t)(c0 + m) * 1024 + kt * 64 + kg * 8;
      load16_to_lds(gb, &sB[(i * 256 + wave * 64) * 8]);
    }
    __syncthreads();
    #pragma unroll
    for (int kkb = 0; kkb < 2; ++kkb) {
      short8 af[4], bf[4];
      int kbyte = kkb * 64 + (lane >> 4) * 16;
      #pragma unroll
      for (int i = 0; i < 4; ++i) {
        int row = wm * 64 + i * 16 + (lane & 15);
        int off = row * 128 + (kbyte ^ ((row & 7) << 4));
        af[i] = *(const short8*)((const char*)sA + off);
        int rowb = wn * 64 + i * 16 + (lane & 15);
        int offb = rowb * 128 + (kbyte ^ ((rowb & 7) << 4));
        bf[i] = *(const short8*)((const char*)sB + offb);
      }
      #pragma unroll
      for (int i = 0; i < 4; ++i)
        #pragma unroll
        for (int jx = 0; jx < 4; ++jx)
          acc[i][jx] = __builtin_amdgcn_mfma_f32_16x16x32_bf16(af[i], bf[jx], acc[i][jx], 0, 0, 0);
    }
  }
  int rbase = r0 + wm * 64 + (lane >> 4) * 4;
  int cbase = c0 + wn * 64 + (lane & 15);
  #pragma unroll
  for (int i = 0; i < 4; ++i)
    #pragma unroll
    for (int jx = 0; jx < 4; ++jx)
      #pragma unroll
      for (int q = 0; q < 4; ++q)
        C[(size_t)(rbase + i * 16 + q) * 32000 + cbase + jx * 16] = acc[i][jx][q];
}

// ---------- launch ----------
extern "C" void kernel_launch(void* const* d_in, const int* in_sizes, int n_in,
                              void* d_out, int out_size, void* d_ws, size_t ws_size,
                              hipStream_t stream) {
  const int* tok = (const int*)d_in[0];
  const float* emb = (const float*)d_in[1];
  const float* Wx = (const float*)d_in[2];
  const float* Wh = (const float*)d_in[3];
  const float* bias = (const float*)d_in[4];
  const float* lmW = (const float*)d_in[5];
  float* out = (float*)d_out;

  const size_t OFF_LMW = 0;                       // bf16 lm_W: 65,536,000
  const size_t OFF_XW = 65536000;                 // f32 xw:   16,777,216
  const size_t OFF_HALL = OFF_XW + 16777216;      // bf16 h_all: 8,388,608
  const size_t OFF_HCMB = OFF_HALL + 8388608;     // u64 hcomb: 2*16*1024*8 = 262,144
  const size_t NEED = OFF_HCMB + 262144;
  if (ws_size < NEED) {
    sentinel_kernel<<<1, 1, 0, stream>>>(out);
    return;
  }
  char* ws = (char*)d_ws;
  unsigned short* lmW_bf = (unsigned short*)(ws + OFF_LMW);
  float* xw = (float*)(ws + OFF_XW);
  unsigned short* h_all = (unsigned short*)(ws + OFF_HALL);
  unsigned long long* hcomb = (unsigned long long*)(ws + OFF_HCMB);

  // tags must restart at 0 EVERY call (graph replay!)
  hipMemsetAsync(ws + OFF_HCMB, 0, 262144, stream);
  cvt_kernel<<<2048, 256, 0, stream>>>(lmW, lmW_bf, 32000 * 1024 / 8);
  xw_kernel<<<1024, 256, 0, stream>>>(tok, emb, Wx, bias, xw);
  rec_kernel<<<256, 1024, 0, stream>>>(Wh, xw, tok, hcomb, h_all);
  gemm_kernel<<<8000, 256, 0, stream>>>(h_all, lmW_bf, out);
}